// Round 5
// baseline (207.323 us; speedup 1.0000x reference)
//
#include <hip/hip_runtime.h>

// ---------------------------------------------------------------------------
// MaskAttentionHead v18: DIAGNOSTIC round. Exact v15 bodies (best: 126.8us),
// but qkv runs its K-loop x4 and flash its si-loop x3, accumulators re-zeroed
// per rep (discarded reps kept live via asm keep-sum -- rule #17 anti-DCE).
// Output is bit-identical to v15. Purpose: push qkv/flash dispatch durations
// past the harness's 41us fill kernels so the rocprof top-5 finally shows
// OUR counters (MfmaUtil/VALUBusy/FETCH/Occupancy per kernel). Absence from
// top-5 is also decisive (upper-bounds the kernel at ~10-14us).
//  v17 post-mortem: cooperative launch produced zero output (launch failed);
//  fusion path abandoned.
// ws: WF 384KB | Qg 2MB | KF 2MB | VF 2MB  (~6.7MB)
// ---------------------------------------------------------------------------

#define QKV_REP  4
#define FLASH_REP 3

typedef __attribute__((ext_vector_type(8))) short v8s;           // 8 x bf16 (MFMA operand)
typedef __attribute__((ext_vector_type(4))) float v4f;           // MFMA 16x16 C/D
typedef __attribute__((ext_vector_type(4))) float f4;            // 4 x f32
typedef __attribute__((ext_vector_type(8))) float f8;            // 8 x f32
typedef __attribute__((ext_vector_type(4))) __bf16 bf4;          // 4 x bf16
typedef __attribute__((ext_vector_type(8))) __bf16 bf8;          // 8 x bf16
typedef __attribute__((ext_vector_type(4))) unsigned short u4;   // 4 x u16

// f32x4 -> bf16x4 (RNE, HW packed cvt on gfx950), as raw u16 lanes.
static __device__ __forceinline__ u4 cvt4(f4 v) {
  return __builtin_bit_cast(u4, __builtin_convertvector(v, bf4));
}

// f32x8 -> bf16x8 as an MFMA A/B operand.
static __device__ __forceinline__ v8s cvt8(f4 lo, f4 hi) {
  f8 ff = __builtin_shufflevector(lo, hi, 0, 1, 2, 3, 4, 5, 6, 7);
  return __builtin_bit_cast(v8s, __builtin_convertvector(ff, bf8));
}

// async 16B/lane global->LDS DMA: dst wave-uniform base, lane i -> dst+i*16.
static __device__ __forceinline__ void dma16(const void* src, void* dst) {
  __builtin_amdgcn_global_load_lds(
      (const __attribute__((address_space(1))) void*)src,
      (__attribute__((address_space(3))) void*)dst, 16, 0, 0);
}

// --- kernel 1: pack weights into WF ----------------------------------------
// WF chunk (g*12+nt)*512 (+lane*8) = B-fragment for 32-K group g, n-tile nt:
// lane(quad,colid) holds W[n=nt*16+colid][k=g*32+quad*8+j].  1/8 folded in Wq.
__global__ __launch_bounds__(256) void pack_w(const float* __restrict__ Wq,
                                              const float* __restrict__ Wk,
                                              const float* __restrict__ Wv,
                                              unsigned short* __restrict__ WF) {
  int idx = (blockIdx.x * 256 + threadIdx.x) * 4;  // 192*1024 total
  int row = idx >> 10;
  int k   = idx & 1023;
  const float* src;
  float scale;
  if (row < 64)       { src = Wq + row * 1024 + k;         scale = 0.125f; }
  else if (row < 128) { src = Wk + (row - 64) * 1024 + k;  scale = 1.0f;   }
  else                { src = Wv + (row - 128) * 1024 + k; scale = 1.0f;   }
  f4 f = *(const f4*)src;
  u4 o = cvt4(f * scale);
  size_t off = ((size_t)(k >> 5) * 12 + (row >> 4)) * 512 +
               (((k >> 3) & 3) * 16 + (row & 15)) * 8 + (k & 7);
  *(u4*)(WF + off) = o;
}

// --- kernel 2: QKV projection (v15 body, K-loop repeated QKV_REP times) -----
// 512 blocks x 256 threads, 32 rows/block. K in 8 steps of 128. LDS unit
// (r, su) at byte r*512 + su*16 holds global unit u = su ^ (r&7).
__global__ __launch_bounds__(256) void qkv(const float* __restrict__ x,
                                           const unsigned short* __restrict__ WF,
                                           unsigned short* __restrict__ Qg,
                                           unsigned short* __restrict__ KF,
                                           unsigned short* __restrict__ VF) {
  __shared__ alignas(16) char xs[2][16384];
  const int tid   = threadIdx.x;
  const int lane  = tid & 63;
  const int wv    = tid >> 6;        // 0..3
  const int quad  = lane >> 4;
  const int colid = lane & 15;
  const int row0  = blockIdx.x * 32;

  const char* xB = (const char*)x;
  const unsigned short* wf = WF + lane * 8;

  const int rpar = lane >> 5;          // which of the chunk's two rows
  const int su_l = lane & 31;          // stored unit
  const int c7   = colid & 7;

  v4f acc[6];   // [mg][ntl] = acc[mg*3+ntl]
#pragma unroll
  for (int i = 0; i < 6; i++) acc[i] = (v4f){0.f, 0.f, 0.f, 0.f};

  auto stage = [&](int kt, int slot) {
#pragma unroll
    for (int i = 0; i < 4; i++) {
      int j    = wv * 4 + i;           // chunk = rows {2j, 2j+1}
      int rloc = 2 * j + rpar;
      int u    = su_l ^ (rloc & 7);    // in-line XOR swizzle
      const char* src = xB + (size_t)(row0 + rloc) * 4096 + kt * 512 + u * 16;
      dma16(src, &xs[slot][j * 1024]);
    }
  };

  for (int rep = 0; rep < QKV_REP; rep++) {
    stage(0, 0);
    for (int kt = 0; kt < 8; kt++) {
      const int slot = kt & 1;
      __syncthreads();                       // drain stage kt
      if (kt < 7) stage(kt + 1, slot ^ 1);   // overlaps compute kt
#pragma unroll
      for (int s = 0; s < 4; s++) {
        const int g = kt * 4 + s;
        v8s bw[3];
#pragma unroll
        for (int ntl = 0; ntl < 3; ntl++)
          bw[ntl] = *(const v8s*)(wf + ((size_t)g * 12 + wv * 3 + ntl) * 512);
#pragma unroll
        for (int mg = 0; mg < 2; mg++) {
          const int rr = mg * 16 + colid;
          const int u0 = s * 8 + quad * 2;
          f4 f0 = *(const f4*)(&xs[slot][rr * 512 + (u0 ^ c7) * 16]);
          f4 f1 = *(const f4*)(&xs[slot][rr * 512 + ((u0 + 1) ^ c7) * 16]);
          v8s a = cvt8(f0, f1);
#pragma unroll
          for (int ntl = 0; ntl < 3; ntl++)
            acc[mg * 3 + ntl] =
                __builtin_amdgcn_mfma_f32_16x16x32_bf16(a, bw[ntl], acc[mg * 3 + ntl], 0, 0, 0);
        }
      }
    }
    if (rep != QKV_REP - 1) {
      // keep rep's results live (anti-DCE), then reset for the next rep
      float keep = 0.f;
#pragma unroll
      for (int i = 0; i < 6; i++)
        keep += acc[i][0] + acc[i][1] + acc[i][2] + acc[i][3];
      asm volatile("" :: "v"(keep));
#pragma unroll
      for (int i = 0; i < 6; i++) acc[i] = (v4f){0.f, 0.f, 0.f, 0.f};
      __syncthreads();   // all waves done with slot1 before rep+1 restages
    }
  }

  // epilogue: wave wv stores n-tiles wv*3..wv*3+2 for both m-groups
#pragma unroll
  for (int ntl = 0; ntl < 3; ntl++) {
    const int nt = wv * 3 + ntl;
#pragma unroll
    for (int mg = 0; mg < 2; mg++) {
      const int trow_base = row0 + mg * 16 + quad * 4;
      const v4f av = acc[mg * 3 + ntl];
      u4 cc = cvt4((f4){av[0], av[1], av[2], av[3]});
      if (nt < 4) {
#pragma unroll
        for (int r = 0; r < 4; r++)
          Qg[(size_t)(trow_base + r) * 64 + nt * 16 + colid] = cc[r];
      } else if (nt < 8) {
        int half = (nt - 4) >> 1;
        int q_f  = ((nt - 4) * 2 + (colid >> 3)) & 3;
        int j    = colid & 7;
#pragma unroll
        for (int r = 0; r < 4; r++) {
          int t  = trow_base + r;
          int b  = t >> 12, tl = t & 4095;
          int si = tl >> 6, sl = tl & 63;
          KF[((size_t)(b * 64 + si) * 8 + (sl >> 4) * 2 + half) * 512 +
             (q_f * 16 + (sl & 15)) * 8 + j] = cc[r];
        }
      } else {
#pragma unroll
        for (int r = 0; r < 4; r++) {
          int t  = trow_base + r;
          int b  = t >> 12, tl = t & 4095;
          int si = tl >> 6;
          int half = (tl >> 5) & 1, q_f = (tl >> 3) & 3, j = tl & 7;
          VF[((size_t)(b * 64 + si) * 8 + (nt - 8) * 2 + half) * 512 +
             (q_f * 16 + colid) * 8 + j] = cc[r];
        }
      }
    }
  }
}

// --- kernel 3: causal flash (v15 body, si-loop repeated FLASH_REP times) ----
__global__ __launch_bounds__(256, 2) void flash(const unsigned short* __restrict__ Qg,
                                                const unsigned short* __restrict__ KF,
                                                const unsigned short* __restrict__ VF,
                                                float* __restrict__ out) {
  __shared__ alignas(16) char smem[4 * 32 * 68 * 4 + 4 * 32 * 4];
  unsigned short* pl = (unsigned short*)smem;
  float* redf = (float*)smem;
  float* lred = (float*)(smem + 4 * 32 * 68 * 4);

  const int tid   = threadIdx.x;
  const int lane  = tid & 63;
  const int wv    = tid >> 6;               // si-split id 0..3
  const int quad  = lane >> 4;
  const int colid = lane & 15;
  const int qt32  = 127 - (int)(blockIdx.x >> 2);   // longest-first
  const int b     = blockIdx.x & 3;
  const int bT    = b * 4096;
  const int row00 = qt32 * 32;
  const int qimax = (row00 + 31) >> 6;

  v8s qf[2][2];
#pragma unroll
  for (int mt = 0; mt < 2; mt++) {
    const unsigned short* qrow =
        Qg + (size_t)(bT + row00 + mt * 16 + colid) * 64 + quad * 8;
    qf[mt][0] = *(const v8s*)(qrow);
    qf[mt][1] = *(const v8s*)(qrow + 32);
  }

  v8s ones;
#pragma unroll
  for (int j = 0; j < 8; j++) ones[j] = (short)0x3F80;  // bf16 1.0

  v4f o[2][4];
  v4f lac[2];
  const unsigned short* kb0 = KF + (size_t)b * 64 * 4096 + lane * 8;
  const unsigned short* vb0 = VF + (size_t)b * 64 * 4096 + lane * 8;

  for (int rep = 0; rep < FLASH_REP; rep++) {
#pragma unroll
    for (int mt = 0; mt < 2; mt++)
#pragma unroll
      for (int i = 0; i < 4; i++) o[mt][i] = (v4f){0.f, 0.f, 0.f, 0.f};
    lac[0] = (v4f){0.f, 0.f, 0.f, 0.f};
    lac[1] = (v4f){0.f, 0.f, 0.f, 0.f};

    for (int si = wv; si <= qimax; si += 4) {
      const unsigned short* ktile = kb0 + (size_t)si * 4096;
      const unsigned short* vtile = vb0 + (size_t)si * 4096;
      v8s ck[8], cv[8];
#pragma unroll
      for (int c = 0; c < 8; c++) ck[c] = *(const v8s*)(ktile + (size_t)c * 512);
#pragma unroll
      for (int c = 0; c < 8; c++) cv[c] = *(const v8s*)(vtile + (size_t)c * 512);

#pragma unroll
      for (int mt = 0; mt < 2; mt++) {
        v4f s[4];
#pragma unroll
        for (int i = 0; i < 4; i++) s[i] = (v4f){0.f, 0.f, 0.f, 0.f};
#pragma unroll
        for (int nt = 0; nt < 4; nt++) {
          s[nt] = __builtin_amdgcn_mfma_f32_16x16x32_bf16(qf[mt][0], ck[2 * nt], s[nt], 0, 0, 0);
          s[nt] = __builtin_amdgcn_mfma_f32_16x16x32_bf16(qf[mt][1], ck[2 * nt + 1], s[nt], 0, 0, 0);
        }

        if (si == qimax) {    // diagonal-containing tile: causal mask
          int rowb = row00 + mt * 16 + quad * 4;
          int colb = si * 64;
#pragma unroll
          for (int nt = 0; nt < 4; nt++)
#pragma unroll
            for (int r = 0; r < 4; r++)
              if (colb + nt * 16 + colid > rowb + r) s[nt][r] = -1e30f;
        }

        unsigned short* pw = pl + (wv * 2 + mt) * (16 * 72);
#pragma unroll
        for (int nt = 0; nt < 4; nt++) {
          f4 ev = {__expf(s[nt][0]), __expf(s[nt][1]),
                   __expf(s[nt][2]), __expf(s[nt][3])};
          u4 p = cvt4(ev);
          unsigned short* pb = pw + quad * 4 * 72 + nt * 16 + colid;
          pb[0]   = p[0];
          pb[72]  = p[1];
          pb[144] = p[2];
          pb[216] = p[3];
        }
      }

#pragma unroll
      for (int mt = 0; mt < 2; mt++) {
        unsigned short* pw = pl + (wv * 2 + mt) * (16 * 72);
#pragma unroll
        for (int ks = 0; ks < 64; ks += 32) {
          v8s af = *(const v8s*)(&pw[colid * 72 + ks + quad * 8]);
          lac[mt] = __builtin_amdgcn_mfma_f32_16x16x32_bf16(af, ones, lac[mt], 0, 0, 0);
#pragma unroll
          for (int nt = 0; nt < 4; nt++)
            o[mt][nt] = __builtin_amdgcn_mfma_f32_16x16x32_bf16(
                af, cv[2 * nt + (ks >> 5)], o[mt][nt], 0, 0, 0);
        }
      }
    }

    if (rep != FLASH_REP - 1) {
      // keep rep's results live (anti-DCE); next rep re-zeroes accumulators
      float keep = 0.f;
#pragma unroll
      for (int mt = 0; mt < 2; mt++) {
#pragma unroll
        for (int nt = 0; nt < 4; nt++)
          keep += o[mt][nt][0] + o[mt][nt][1] + o[mt][nt][2] + o[mt][nt][3];
        keep += lac[mt][0] + lac[mt][1] + lac[mt][2] + lac[mt][3];
      }
      asm volatile("" :: "v"(keep));
    }
  }

  __syncthreads();
#pragma unroll
  for (int mt = 0; mt < 2; mt++) {
#pragma unroll
    for (int nt = 0; nt < 4; nt++)
#pragma unroll
      for (int r = 0; r < 4; r++)
        redf[(wv * 32 + mt * 16 + quad * 4 + r) * 68 + nt * 16 + colid] = o[mt][nt][r];
    if (colid == 0) {
#pragma unroll
      for (int r = 0; r < 4; r++)
        lred[wv * 32 + mt * 16 + quad * 4 + r] = lac[mt][r];
    }
  }
  __syncthreads();

  {
    int col = tid & 63;
    int r0  = tid >> 6;
#pragma unroll
    for (int rr = 0; rr < 8; rr++) {
      int row = r0 * 8 + rr;
      float sum = 0.f, lsum = 0.f;
#pragma unroll
      for (int w = 0; w < 4; w++) {
        sum  += redf[(w * 32 + row) * 68 + col];
        lsum += lred[w * 32 + row];
      }
      out[(size_t)(bT + row00 + row) * 64 + col] = sum / lsum;
    }
  }
}

extern "C" void kernel_launch(void* const* d_in, const int* in_sizes, int n_in,
                              void* d_out, int out_size, void* d_ws, size_t ws_size,
                              hipStream_t stream) {
  const float* x  = (const float*)d_in[0];
  const float* Wq = (const float*)d_in[1];
  const float* Wk = (const float*)d_in[2];
  const float* Wv = (const float*)d_in[3];
  float* out = (float*)d_out;

  unsigned short* WF = (unsigned short*)d_ws;          // 192*1024
  unsigned short* Qg = WF + 192 * 1024;                // 16384*64 row-major
  unsigned short* KF = Qg + 16384 * 64;                // fragment-linear
  unsigned short* VF = KF + 16384 * 64;                // fragment-linear

  hipLaunchKernelGGL(pack_w, dim3(192), dim3(256), 0, stream, Wq, Wk, Wv, WF);
  hipLaunchKernelGGL(qkv, dim3(512), dim3(256), 0, stream, x, WF, Qg, KF, VF);
  hipLaunchKernelGGL(flash, dim3(512), dim3(256), 0, stream, Qg, KF, VF, out);
}

// Round 6
// 129.680 us; speedup vs baseline: 1.5987x; 1.5987x over previous
//
#include <hip/hip_runtime.h>

// ---------------------------------------------------------------------------
// MaskAttentionHead v19: qkv WF-amortization. Evidence from v18 diagnostics:
//  qkv ~20us (MfmaUtil 12 / VALU 18 / HBM 22 / Occ 21.6 -> latency-bound,
//  70% SIMD idle), flash ~10us, harness fixed ~95us.
//  qkv: 256 blocks x 512 threads x 64 rows (was 512x256x32):
//   - WF L2 re-read traffic halves (197MB -> 98MB; wave pairs share chunks
//     -> L1 hits cut further)
//   - barrier count per row halves (8 barriers / 64 rows)
//   - same 8 waves/CU, same per-lane DMA + XOR swizzle + fragment math.
//  flash, pack_w: exact v15 bodies (unchanged).
// ws: WF 384KB | Qg 2MB | KF 2MB | VF 2MB  (~6.7MB)
// ---------------------------------------------------------------------------

typedef __attribute__((ext_vector_type(8))) short v8s;           // 8 x bf16 (MFMA operand)
typedef __attribute__((ext_vector_type(4))) float v4f;           // MFMA 16x16 C/D
typedef __attribute__((ext_vector_type(4))) float f4;            // 4 x f32
typedef __attribute__((ext_vector_type(8))) float f8;            // 8 x f32
typedef __attribute__((ext_vector_type(4))) __bf16 bf4;          // 4 x bf16
typedef __attribute__((ext_vector_type(8))) __bf16 bf8;          // 8 x bf16
typedef __attribute__((ext_vector_type(4))) unsigned short u4;   // 4 x u16

// f32x4 -> bf16x4 (RNE, HW packed cvt on gfx950), as raw u16 lanes.
static __device__ __forceinline__ u4 cvt4(f4 v) {
  return __builtin_bit_cast(u4, __builtin_convertvector(v, bf4));
}

// f32x8 -> bf16x8 as an MFMA A/B operand.
static __device__ __forceinline__ v8s cvt8(f4 lo, f4 hi) {
  f8 ff = __builtin_shufflevector(lo, hi, 0, 1, 2, 3, 4, 5, 6, 7);
  return __builtin_bit_cast(v8s, __builtin_convertvector(ff, bf8));
}

// async 16B/lane global->LDS DMA: dst wave-uniform base, lane i -> dst+i*16.
static __device__ __forceinline__ void dma16(const void* src, void* dst) {
  __builtin_amdgcn_global_load_lds(
      (const __attribute__((address_space(1))) void*)src,
      (__attribute__((address_space(3))) void*)dst, 16, 0, 0);
}

// --- kernel 1: pack weights into WF ----------------------------------------
// WF chunk (g*12+nt)*512 (+lane*8) = B-fragment for 32-K group g, n-tile nt:
// lane(quad,colid) holds W[n=nt*16+colid][k=g*32+quad*8+j].  1/8 folded in Wq.
__global__ __launch_bounds__(256) void pack_w(const float* __restrict__ Wq,
                                              const float* __restrict__ Wk,
                                              const float* __restrict__ Wv,
                                              unsigned short* __restrict__ WF) {
  int idx = (blockIdx.x * 256 + threadIdx.x) * 4;  // 192*1024 total
  int row = idx >> 10;
  int k   = idx & 1023;
  const float* src;
  float scale;
  if (row < 64)       { src = Wq + row * 1024 + k;         scale = 0.125f; }
  else if (row < 128) { src = Wk + (row - 64) * 1024 + k;  scale = 1.0f;   }
  else                { src = Wv + (row - 128) * 1024 + k; scale = 1.0f;   }
  f4 f = *(const f4*)src;
  u4 o = cvt4(f * scale);
  size_t off = ((size_t)(k >> 5) * 12 + (row >> 4)) * 512 +
               (((k >> 3) & 3) * 16 + (row & 15)) * 8 + (k & 7);
  *(u4*)(WF + off) = o;
}

// --- kernel 2: QKV projection ----------------------------------------------
// 256 blocks x 512 threads (8 waves), 64 rows/block. K in 8 steps of 128
// (= 32 16-B units/row/step). LDS unit (r, su) at byte r*512 + su*16 holds
// global unit u = su ^ (r&7) (XOR inside a 128-B line -> DMA coalescing
// intact, ds_read banks spread). Wave wv stages chunks j in [wv*4,wv*4+4)
// (chunk j = rows {2j,2j+1}). Work split: nw = wv&3 -> n-tiles
// {nw*3..nw*3+2}; mh = wv>>2 -> m-groups {2mh, 2mh+1} (rows mh*32..mh*32+31).
__global__ __launch_bounds__(512) void qkv(const float* __restrict__ x,
                                           const unsigned short* __restrict__ WF,
                                           unsigned short* __restrict__ Qg,
                                           unsigned short* __restrict__ KF,
                                           unsigned short* __restrict__ VF) {
  __shared__ alignas(16) char xs[2][32768];
  const int tid   = threadIdx.x;
  const int lane  = tid & 63;
  const int wv    = tid >> 6;        // 0..7
  const int nw    = wv & 3;          // n-split
  const int mh    = wv >> 2;         // m-half
  const int quad  = lane >> 4;
  const int colid = lane & 15;
  const int row0  = blockIdx.x * 64;

  const char* xB = (const char*)x;
  const unsigned short* wf = WF + lane * 8;

  // per-lane DMA source pieces: rloc = 2j + (lane>>5), su = lane&31
  const int rpar = lane >> 5;          // which of the chunk's two rows
  const int su_l = lane & 31;          // stored unit
  const int c7   = colid & 7;

  v4f acc[6];   // [l][ntl] = acc[l*3+ntl], l = local m-group (0,1)
#pragma unroll
  for (int i = 0; i < 6; i++) acc[i] = (v4f){0.f, 0.f, 0.f, 0.f};

  auto stage = [&](int kt, int slot) {
#pragma unroll
    for (int i = 0; i < 4; i++) {
      int j    = wv * 4 + i;           // chunk = rows {2j, 2j+1}, j 0..31
      int rloc = 2 * j + rpar;
      int u    = su_l ^ (rloc & 7);    // in-line XOR swizzle
      const char* src = xB + (size_t)(row0 + rloc) * 4096 + kt * 512 + u * 16;
      dma16(src, &xs[slot][j * 1024]);
    }
  };

  stage(0, 0);

  for (int kt = 0; kt < 8; kt++) {
    const int slot = kt & 1;
    __syncthreads();                       // drain stage kt
    if (kt < 7) stage(kt + 1, slot ^ 1);   // overlaps compute kt
#pragma unroll
    for (int s = 0; s < 4; s++) {
      const int g = kt * 4 + s;
      v8s bw[3];
#pragma unroll
      for (int ntl = 0; ntl < 3; ntl++)
        bw[ntl] = *(const v8s*)(wf + ((size_t)g * 12 + nw * 3 + ntl) * 512);
#pragma unroll
      for (int l = 0; l < 2; l++) {
        const int rr = mh * 32 + l * 16 + colid;   // local row 0..63
        const int u0 = s * 8 + quad * 2;
        f4 f0 = *(const f4*)(&xs[slot][rr * 512 + (u0 ^ c7) * 16]);
        f4 f1 = *(const f4*)(&xs[slot][rr * 512 + ((u0 + 1) ^ c7) * 16]);
        v8s a = cvt8(f0, f1);
#pragma unroll
        for (int ntl = 0; ntl < 3; ntl++)
          acc[l * 3 + ntl] =
              __builtin_amdgcn_mfma_f32_16x16x32_bf16(a, bw[ntl], acc[l * 3 + ntl], 0, 0, 0);
      }
    }
  }

  // epilogue: wave (nw, mh) stores n-tiles nw*3..nw*3+2 for m-groups 2mh,2mh+1
#pragma unroll
  for (int ntl = 0; ntl < 3; ntl++) {
    const int nt = nw * 3 + ntl;
#pragma unroll
    for (int l = 0; l < 2; l++) {
      const int trow_base = row0 + (mh * 2 + l) * 16 + quad * 4;
      const v4f av = acc[l * 3 + ntl];
      u4 cc = cvt4((f4){av[0], av[1], av[2], av[3]});
      if (nt < 4) {
#pragma unroll
        for (int r = 0; r < 4; r++)
          Qg[(size_t)(trow_base + r) * 64 + nt * 16 + colid] = cc[r];
      } else if (nt < 8) {
        int half = (nt - 4) >> 1;
        int q_f  = ((nt - 4) * 2 + (colid >> 3)) & 3;
        int j    = colid & 7;
#pragma unroll
        for (int r = 0; r < 4; r++) {
          int t  = trow_base + r;
          int b  = t >> 12, tl = t & 4095;
          int si = tl >> 6, sl = tl & 63;
          KF[((size_t)(b * 64 + si) * 8 + (sl >> 4) * 2 + half) * 512 +
             (q_f * 16 + (sl & 15)) * 8 + j] = cc[r];
        }
      } else {
#pragma unroll
        for (int r = 0; r < 4; r++) {
          int t  = trow_base + r;
          int b  = t >> 12, tl = t & 4095;
          int si = tl >> 6;
          int half = (tl >> 5) & 1, q_f = (tl >> 3) & 3, j = tl & 7;
          VF[((size_t)(b * 64 + si) * 8 + (nt - 8) * 2 + half) * 512 +
             (q_f * 16 + colid) * 8 + j] = cc[r];
        }
      }
    }
  }
}

// --- kernel 3: causal flash, BM=32/wave, 4-way si-split (v15 body) ----------
__global__ __launch_bounds__(256, 2) void flash(const unsigned short* __restrict__ Qg,
                                                const unsigned short* __restrict__ KF,
                                                const unsigned short* __restrict__ VF,
                                                float* __restrict__ out) {
  __shared__ alignas(16) char smem[4 * 32 * 68 * 4 + 4 * 32 * 4];
  unsigned short* pl = (unsigned short*)smem;
  float* redf = (float*)smem;
  float* lred = (float*)(smem + 4 * 32 * 68 * 4);

  const int tid   = threadIdx.x;
  const int lane  = tid & 63;
  const int wv    = tid >> 6;               // si-split id 0..3
  const int quad  = lane >> 4;
  const int colid = lane & 15;
  const int qt32  = 127 - (int)(blockIdx.x >> 2);   // longest-first
  const int b     = blockIdx.x & 3;
  const int bT    = b * 4096;
  const int row00 = qt32 * 32;
  const int qimax = (row00 + 31) >> 6;

  v8s qf[2][2];
#pragma unroll
  for (int mt = 0; mt < 2; mt++) {
    const unsigned short* qrow =
        Qg + (size_t)(bT + row00 + mt * 16 + colid) * 64 + quad * 8;
    qf[mt][0] = *(const v8s*)(qrow);
    qf[mt][1] = *(const v8s*)(qrow + 32);
  }

  v8s ones;
#pragma unroll
  for (int j = 0; j < 8; j++) ones[j] = (short)0x3F80;  // bf16 1.0

  v4f o[2][4];
#pragma unroll
  for (int mt = 0; mt < 2; mt++)
#pragma unroll
    for (int i = 0; i < 4; i++) o[mt][i] = (v4f){0.f, 0.f, 0.f, 0.f};
  v4f lac[2];
  lac[0] = (v4f){0.f, 0.f, 0.f, 0.f};
  lac[1] = (v4f){0.f, 0.f, 0.f, 0.f};

  const unsigned short* kb0 = KF + (size_t)b * 64 * 4096 + lane * 8;
  const unsigned short* vb0 = VF + (size_t)b * 64 * 4096 + lane * 8;

  for (int si = wv; si <= qimax; si += 4) {
    const unsigned short* ktile = kb0 + (size_t)si * 4096;
    const unsigned short* vtile = vb0 + (size_t)si * 4096;
    v8s ck[8], cv[8];
#pragma unroll
    for (int c = 0; c < 8; c++) ck[c] = *(const v8s*)(ktile + (size_t)c * 512);
#pragma unroll
    for (int c = 0; c < 8; c++) cv[c] = *(const v8s*)(vtile + (size_t)c * 512);

#pragma unroll
    for (int mt = 0; mt < 2; mt++) {
      v4f s[4];
#pragma unroll
      for (int i = 0; i < 4; i++) s[i] = (v4f){0.f, 0.f, 0.f, 0.f};
#pragma unroll
      for (int nt = 0; nt < 4; nt++) {
        s[nt] = __builtin_amdgcn_mfma_f32_16x16x32_bf16(qf[mt][0], ck[2 * nt], s[nt], 0, 0, 0);
        s[nt] = __builtin_amdgcn_mfma_f32_16x16x32_bf16(qf[mt][1], ck[2 * nt + 1], s[nt], 0, 0, 0);
      }

      if (si == qimax) {    // diagonal-containing tile: causal mask
        int rowb = row00 + mt * 16 + quad * 4;
        int colb = si * 64;
#pragma unroll
        for (int nt = 0; nt < 4; nt++)
#pragma unroll
          for (int r = 0; r < 4; r++)
            if (colb + nt * 16 + colid > rowb + r) s[nt][r] = -1e30f;
      }

      unsigned short* pw = pl + (wv * 2 + mt) * (16 * 72);
#pragma unroll
      for (int nt = 0; nt < 4; nt++) {
        f4 ev = {__expf(s[nt][0]), __expf(s[nt][1]),
                 __expf(s[nt][2]), __expf(s[nt][3])};
        u4 p = cvt4(ev);
        unsigned short* pb = pw + quad * 4 * 72 + nt * 16 + colid;
        pb[0]   = p[0];
        pb[72]  = p[1];
        pb[144] = p[2];
        pb[216] = p[3];
      }
    }

#pragma unroll
    for (int mt = 0; mt < 2; mt++) {
      unsigned short* pw = pl + (wv * 2 + mt) * (16 * 72);
#pragma unroll
      for (int ks = 0; ks < 64; ks += 32) {
        v8s af = *(const v8s*)(&pw[colid * 72 + ks + quad * 8]);
        lac[mt] = __builtin_amdgcn_mfma_f32_16x16x32_bf16(af, ones, lac[mt], 0, 0, 0);
#pragma unroll
        for (int nt = 0; nt < 4; nt++)
          o[mt][nt] = __builtin_amdgcn_mfma_f32_16x16x32_bf16(
              af, cv[2 * nt + (ks >> 5)], o[mt][nt], 0, 0, 0);
      }
    }
  }

  __syncthreads();
#pragma unroll
  for (int mt = 0; mt < 2; mt++) {
#pragma unroll
    for (int nt = 0; nt < 4; nt++)
#pragma unroll
      for (int r = 0; r < 4; r++)
        redf[(wv * 32 + mt * 16 + quad * 4 + r) * 68 + nt * 16 + colid] = o[mt][nt][r];
    if (colid == 0) {
#pragma unroll
      for (int r = 0; r < 4; r++)
        lred[wv * 32 + mt * 16 + quad * 4 + r] = lac[mt][r];
    }
  }
  __syncthreads();

  {
    int col = tid & 63;
    int r0  = tid >> 6;
#pragma unroll
    for (int rr = 0; rr < 8; rr++) {
      int row = r0 * 8 + rr;
      float sum = 0.f, lsum = 0.f;
#pragma unroll
      for (int w = 0; w < 4; w++) {
        sum  += redf[(w * 32 + row) * 68 + col];
        lsum += lred[w * 32 + row];
      }
      out[(size_t)(bT + row00 + row) * 64 + col] = sum / lsum;
    }
  }
}

extern "C" void kernel_launch(void* const* d_in, const int* in_sizes, int n_in,
                              void* d_out, int out_size, void* d_ws, size_t ws_size,
                              hipStream_t stream) {
  const float* x  = (const float*)d_in[0];
  const float* Wq = (const float*)d_in[1];
  const float* Wk = (const float*)d_in[2];
  const float* Wv = (const float*)d_in[3];
  float* out = (float*)d_out;

  unsigned short* WF = (unsigned short*)d_ws;          // 192*1024
  unsigned short* Qg = WF + 192 * 1024;                // 16384*64 row-major
  unsigned short* KF = Qg + 16384 * 64;                // fragment-linear
  unsigned short* VF = KF + 16384 * 64;                // fragment-linear

  hipLaunchKernelGGL(pack_w, dim3(192), dim3(256), 0, stream, Wq, Wk, Wv, WF);
  hipLaunchKernelGGL(qkv, dim3(256), dim3(512), 0, stream, x, WF, Qg, KF, VF);
  hipLaunchKernelGGL(flash, dim3(512), dim3(256), 0, stream, Qg, KF, VF, out);
}

// Round 7
// 129.328 us; speedup vs baseline: 1.6031x; 1.0027x over previous
//
#include <hip/hip_runtime.h>

// ---------------------------------------------------------------------------
// MaskAttentionHead v20: producer/consumer qkv.
//  Theory (from v18 counters + m135 vmcnt semantics): v15's compute MFMAs
//  consume bw L2-loads that are YOUNGER than the just-issued stage HBM
//  loads; vmcnt retires oldest-first, so every K-step's first MFMA waits
//  ~900cy for the NEXT tile's HBM staging. Fix: vmcnt ordering is per-wave
//  -> move all staging to a dedicated producer wave.
//  qkv: 512 blocks x 320 threads. Wave 4 = producer: 3-slot LDS, 2-deep
//  prefetch, counted vmcnt(16) (never 0 until drain). Waves 0-3 = consumers:
//  exact v15 compute + epilogue, bw fragments double-buffered 1 K-step ahead
//  (consumer vmcnt chain = own L2 loads only). Raw s_barrier + sched_barrier
//  fences (rule #18). flash, pack_w: exact v15 bodies.
// ws: WF 384KB | Qg 2MB | KF 2MB | VF 2MB  (~6.7MB)
// ---------------------------------------------------------------------------

typedef __attribute__((ext_vector_type(8))) short v8s;           // 8 x bf16 (MFMA operand)
typedef __attribute__((ext_vector_type(4))) float v4f;           // MFMA 16x16 C/D
typedef __attribute__((ext_vector_type(4))) float f4;            // 4 x f32
typedef __attribute__((ext_vector_type(8))) float f8;            // 8 x f32
typedef __attribute__((ext_vector_type(4))) __bf16 bf4;          // 4 x bf16
typedef __attribute__((ext_vector_type(8))) __bf16 bf8;          // 8 x bf16
typedef __attribute__((ext_vector_type(4))) unsigned short u4;   // 4 x u16

// f32x4 -> bf16x4 (RNE, HW packed cvt on gfx950), as raw u16 lanes.
static __device__ __forceinline__ u4 cvt4(f4 v) {
  return __builtin_bit_cast(u4, __builtin_convertvector(v, bf4));
}

// f32x8 -> bf16x8 as an MFMA A/B operand.
static __device__ __forceinline__ v8s cvt8(f4 lo, f4 hi) {
  f8 ff = __builtin_shufflevector(lo, hi, 0, 1, 2, 3, 4, 5, 6, 7);
  return __builtin_bit_cast(v8s, __builtin_convertvector(ff, bf8));
}

// async 16B/lane global->LDS DMA: dst wave-uniform base, lane i -> dst+i*16.
static __device__ __forceinline__ void dma16(const void* src, void* dst) {
  __builtin_amdgcn_global_load_lds(
      (const __attribute__((address_space(1))) void*)src,
      (__attribute__((address_space(3))) void*)dst, 16, 0, 0);
}

// --- kernel 1: pack weights into WF ----------------------------------------
// WF chunk (g*12+nt)*512 (+lane*8) = B-fragment for 32-K group g, n-tile nt:
// lane(quad,colid) holds W[n=nt*16+colid][k=g*32+quad*8+j].  1/8 folded in Wq.
__global__ __launch_bounds__(256) void pack_w(const float* __restrict__ Wq,
                                              const float* __restrict__ Wk,
                                              const float* __restrict__ Wv,
                                              unsigned short* __restrict__ WF) {
  int idx = (blockIdx.x * 256 + threadIdx.x) * 4;  // 192*1024 total
  int row = idx >> 10;
  int k   = idx & 1023;
  const float* src;
  float scale;
  if (row < 64)       { src = Wq + row * 1024 + k;         scale = 0.125f; }
  else if (row < 128) { src = Wk + (row - 64) * 1024 + k;  scale = 1.0f;   }
  else                { src = Wv + (row - 128) * 1024 + k; scale = 1.0f;   }
  f4 f = *(const f4*)src;
  u4 o = cvt4(f * scale);
  size_t off = ((size_t)(k >> 5) * 12 + (row >> 4)) * 512 +
               (((k >> 3) & 3) * 16 + (row & 15)) * 8 + (k & 7);
  *(u4*)(WF + off) = o;
}

// --- kernel 2: QKV projection (producer/consumer) ---------------------------
// 512 blocks x 320 threads, 32 rows/block. K in 8 steps of 128. LDS: 3 slots
// of 16KB; slot(kt) = kt%3. LDS unit (r, su) at byte r*512 + su*16 holds
// global unit u = su ^ (r&7) (XOR inside a 128-B line).
// Wave 4 (producer): stages tile kt+2 each step; vmcnt(16) = exactly
// "stage(kt) landed, stage(kt+1)/(kt+2) in flight".
// Waves 0-3 (consumers): wave wv computes n-tiles {wv*3..wv*3+2} x both
// m-groups; bw fragments double-buffered one K-step ahead.
__global__ __launch_bounds__(320) void qkv(const float* __restrict__ x,
                                           const unsigned short* __restrict__ WF,
                                           unsigned short* __restrict__ Qg,
                                           unsigned short* __restrict__ KF,
                                           unsigned short* __restrict__ VF) {
  __shared__ alignas(16) char xs[3][16384];
  const int tid   = threadIdx.x;
  const int lane  = tid & 63;
  const int wv    = tid >> 6;        // 0..4
  const int quad  = lane >> 4;
  const int colid = lane & 15;
  const int row0  = blockIdx.x * 32;

  const char* xB = (const char*)x;

  if (wv == 4) {
    // ---------------- producer wave ----------------
    const int rpar = lane >> 5;        // row within a 2-row chunk
    const int su_l = lane & 31;        // stored unit
    auto stage = [&](int kt, int slot) {
#pragma unroll
      for (int t = 0; t < 16; t++) {   // chunk t = rows {2t, 2t+1}
        int rloc = 2 * t + rpar;
        int u    = su_l ^ (rloc & 7);  // in-line XOR swizzle
        const char* src = xB + (size_t)(row0 + rloc) * 4096 + kt * 512 + u * 16;
        dma16(src, &xs[slot][t * 1024]);
      }
    };
    stage(0, 0);
    stage(1, 1);
#pragma unroll
    for (int kt = 0; kt < 8; kt++) {
      if (kt < 7) asm volatile("s_waitcnt vmcnt(16)" ::: "memory");
      else        asm volatile("s_waitcnt vmcnt(0)"  ::: "memory");
      __builtin_amdgcn_sched_barrier(0);
      __builtin_amdgcn_s_barrier();          // consumers may now read slot kt%3
      __builtin_amdgcn_sched_barrier(0);
      if (kt < 6) stage(kt + 2, (kt + 2) % 3);
    }
    return;  // no epilogue work
  }

  // ---------------- consumer waves (0..3) ----------------
  const unsigned short* wf = WF + lane * 8;
  const int c7 = colid & 7;

  v4f acc[6];   // [mg][ntl] = acc[mg*3+ntl]
#pragma unroll
  for (int i = 0; i < 6; i++) acc[i] = (v4f){0.f, 0.f, 0.f, 0.f};

  v8s bwA[12], bwB[12];
  auto load_bw = [&](int kt, v8s* dst) {
#pragma unroll
    for (int s = 0; s < 4; s++)
#pragma unroll
      for (int ntl = 0; ntl < 3; ntl++)
        dst[s * 3 + ntl] =
            *(const v8s*)(wf + ((size_t)(kt * 4 + s) * 12 + wv * 3 + ntl) * 512);
  };
  load_bw(0, bwA);

#pragma unroll
  for (int kt = 0; kt < 8; kt++) {
    __builtin_amdgcn_s_barrier();            // producer guaranteed slot kt%3
    __builtin_amdgcn_sched_barrier(0);       // no ds_read hoist above barrier
    v8s* cur = ((kt & 1) == 0) ? bwA : bwB;
    v8s* nxt = ((kt & 1) == 0) ? bwB : bwA;
    if (kt < 7) load_bw(kt + 1, nxt);        // younger than cur -> never blocks
    const int slot = kt % 3;
#pragma unroll
    for (int s = 0; s < 4; s++) {
#pragma unroll
      for (int mg = 0; mg < 2; mg++) {
        const int rr = mg * 16 + colid;
        const int u0 = s * 8 + quad * 2;
        f4 f0 = *(const f4*)(&xs[slot][rr * 512 + (u0 ^ c7) * 16]);
        f4 f1 = *(const f4*)(&xs[slot][rr * 512 + ((u0 + 1) ^ c7) * 16]);
        v8s a = cvt8(f0, f1);
#pragma unroll
        for (int ntl = 0; ntl < 3; ntl++)
          acc[mg * 3 + ntl] =
              __builtin_amdgcn_mfma_f32_16x16x32_bf16(a, cur[s * 3 + ntl],
                                                      acc[mg * 3 + ntl], 0, 0, 0);
      }
    }
    __builtin_amdgcn_sched_barrier(0);       // no ds_read sink below next barrier
  }

  // epilogue: wave wv stores n-tiles wv*3..wv*3+2 for both m-groups
#pragma unroll
  for (int ntl = 0; ntl < 3; ntl++) {
    const int nt = wv * 3 + ntl;
#pragma unroll
    for (int mg = 0; mg < 2; mg++) {
      const int trow_base = row0 + mg * 16 + quad * 4;
      const v4f av = acc[mg * 3 + ntl];
      u4 cc = cvt4((f4){av[0], av[1], av[2], av[3]});
      if (nt < 4) {
#pragma unroll
        for (int r = 0; r < 4; r++)
          Qg[(size_t)(trow_base + r) * 64 + nt * 16 + colid] = cc[r];
      } else if (nt < 8) {
        int half = (nt - 4) >> 1;
        int q_f  = ((nt - 4) * 2 + (colid >> 3)) & 3;
        int j    = colid & 7;
#pragma unroll
        for (int r = 0; r < 4; r++) {
          int t  = trow_base + r;
          int b  = t >> 12, tl = t & 4095;
          int si = tl >> 6, sl = tl & 63;
          KF[((size_t)(b * 64 + si) * 8 + (sl >> 4) * 2 + half) * 512 +
             (q_f * 16 + (sl & 15)) * 8 + j] = cc[r];
        }
      } else {
#pragma unroll
        for (int r = 0; r < 4; r++) {
          int t  = trow_base + r;
          int b  = t >> 12, tl = t & 4095;
          int si = tl >> 6;
          int half = (tl >> 5) & 1, q_f = (tl >> 3) & 3, j = tl & 7;
          VF[((size_t)(b * 64 + si) * 8 + (nt - 8) * 2 + half) * 512 +
             (q_f * 16 + colid) * 8 + j] = cc[r];
        }
      }
    }
  }
}

// --- kernel 3: causal flash, BM=32/wave, 4-way si-split (v15 body) ----------
__global__ __launch_bounds__(256, 2) void flash(const unsigned short* __restrict__ Qg,
                                                const unsigned short* __restrict__ KF,
                                                const unsigned short* __restrict__ VF,
                                                float* __restrict__ out) {
  __shared__ alignas(16) char smem[4 * 32 * 68 * 4 + 4 * 32 * 4];
  unsigned short* pl = (unsigned short*)smem;
  float* redf = (float*)smem;
  float* lred = (float*)(smem + 4 * 32 * 68 * 4);

  const int tid   = threadIdx.x;
  const int lane  = tid & 63;
  const int wv    = tid >> 6;               // si-split id 0..3
  const int quad  = lane >> 4;
  const int colid = lane & 15;
  const int qt32  = 127 - (int)(blockIdx.x >> 2);   // longest-first
  const int b     = blockIdx.x & 3;
  const int bT    = b * 4096;
  const int row00 = qt32 * 32;
  const int qimax = (row00 + 31) >> 6;

  v8s qf[2][2];
#pragma unroll
  for (int mt = 0; mt < 2; mt++) {
    const unsigned short* qrow =
        Qg + (size_t)(bT + row00 + mt * 16 + colid) * 64 + quad * 8;
    qf[mt][0] = *(const v8s*)(qrow);
    qf[mt][1] = *(const v8s*)(qrow + 32);
  }

  v8s ones;
#pragma unroll
  for (int j = 0; j < 8; j++) ones[j] = (short)0x3F80;  // bf16 1.0

  v4f o[2][4];
#pragma unroll
  for (int mt = 0; mt < 2; mt++)
#pragma unroll
    for (int i = 0; i < 4; i++) o[mt][i] = (v4f){0.f, 0.f, 0.f, 0.f};
  v4f lac[2];
  lac[0] = (v4f){0.f, 0.f, 0.f, 0.f};
  lac[1] = (v4f){0.f, 0.f, 0.f, 0.f};

  const unsigned short* kb0 = KF + (size_t)b * 64 * 4096 + lane * 8;
  const unsigned short* vb0 = VF + (size_t)b * 64 * 4096 + lane * 8;

  for (int si = wv; si <= qimax; si += 4) {
    const unsigned short* ktile = kb0 + (size_t)si * 4096;
    const unsigned short* vtile = vb0 + (size_t)si * 4096;
    v8s ck[8], cv[8];
#pragma unroll
    for (int c = 0; c < 8; c++) ck[c] = *(const v8s*)(ktile + (size_t)c * 512);
#pragma unroll
    for (int c = 0; c < 8; c++) cv[c] = *(const v8s*)(vtile + (size_t)c * 512);

#pragma unroll
    for (int mt = 0; mt < 2; mt++) {
      v4f s[4];
#pragma unroll
      for (int i = 0; i < 4; i++) s[i] = (v4f){0.f, 0.f, 0.f, 0.f};
#pragma unroll
      for (int nt = 0; nt < 4; nt++) {
        s[nt] = __builtin_amdgcn_mfma_f32_16x16x32_bf16(qf[mt][0], ck[2 * nt], s[nt], 0, 0, 0);
        s[nt] = __builtin_amdgcn_mfma_f32_16x16x32_bf16(qf[mt][1], ck[2 * nt + 1], s[nt], 0, 0, 0);
      }

      if (si == qimax) {    // diagonal-containing tile: causal mask
        int rowb = row00 + mt * 16 + quad * 4;
        int colb = si * 64;
#pragma unroll
        for (int nt = 0; nt < 4; nt++)
#pragma unroll
          for (int r = 0; r < 4; r++)
            if (colb + nt * 16 + colid > rowb + r) s[nt][r] = -1e30f;
      }

      unsigned short* pw = pl + (wv * 2 + mt) * (16 * 72);
#pragma unroll
      for (int nt = 0; nt < 4; nt++) {
        f4 ev = {__expf(s[nt][0]), __expf(s[nt][1]),
                 __expf(s[nt][2]), __expf(s[nt][3])};
        u4 p = cvt4(ev);
        unsigned short* pb = pw + quad * 4 * 72 + nt * 16 + colid;
        pb[0]   = p[0];
        pb[72]  = p[1];
        pb[144] = p[2];
        pb[216] = p[3];
      }
    }

#pragma unroll
    for (int mt = 0; mt < 2; mt++) {
      unsigned short* pw = pl + (wv * 2 + mt) * (16 * 72);
#pragma unroll
      for (int ks = 0; ks < 64; ks += 32) {
        v8s af = *(const v8s*)(&pw[colid * 72 + ks + quad * 8]);
        lac[mt] = __builtin_amdgcn_mfma_f32_16x16x32_bf16(af, ones, lac[mt], 0, 0, 0);
#pragma unroll
        for (int nt = 0; nt < 4; nt++)
          o[mt][nt] = __builtin_amdgcn_mfma_f32_16x16x32_bf16(
              af, cv[2 * nt + (ks >> 5)], o[mt][nt], 0, 0, 0);
      }
    }
  }

  __syncthreads();
#pragma unroll
  for (int mt = 0; mt < 2; mt++) {
#pragma unroll
    for (int nt = 0; nt < 4; nt++)
#pragma unroll
      for (int r = 0; r < 4; r++)
        redf[(wv * 32 + mt * 16 + quad * 4 + r) * 68 + nt * 16 + colid] = o[mt][nt][r];
    if (colid == 0) {
#pragma unroll
      for (int r = 0; r < 4; r++)
        lred[wv * 32 + mt * 16 + quad * 4 + r] = lac[mt][r];
    }
  }
  __syncthreads();

  {
    int col = tid & 63;
    int r0  = tid >> 6;
#pragma unroll
    for (int rr = 0; rr < 8; rr++) {
      int row = r0 * 8 + rr;
      float sum = 0.f, lsum = 0.f;
#pragma unroll
      for (int w = 0; w < 4; w++) {
        sum  += redf[(w * 32 + row) * 68 + col];
        lsum += lred[w * 32 + row];
      }
      out[(size_t)(bT + row00 + row) * 64 + col] = sum / lsum;
    }
  }
}

extern "C" void kernel_launch(void* const* d_in, const int* in_sizes, int n_in,
                              void* d_out, int out_size, void* d_ws, size_t ws_size,
                              hipStream_t stream) {
  const float* x  = (const float*)d_in[0];
  const float* Wq = (const float*)d_in[1];
  const float* Wk = (const float*)d_in[2];
  const float* Wv = (const float*)d_in[3];
  float* out = (float*)d_out;

  unsigned short* WF = (unsigned short*)d_ws;          // 192*1024
  unsigned short* Qg = WF + 192 * 1024;                // 16384*64 row-major
  unsigned short* KF = Qg + 16384 * 64;                // fragment-linear
  unsigned short* VF = KF + 16384 * 64;                // fragment-linear

  hipLaunchKernelGGL(pack_w, dim3(192), dim3(256), 0, stream, Wq, Wk, Wv, WF);
  hipLaunchKernelGGL(qkv, dim3(512), dim3(320), 0, stream, x, WF, Qg, KF, VF);
  hipLaunchKernelGGL(flash, dim3(512), dim3(256), 0, stream, Qg, KF, VF, out);
}

// Round 8
// 128.684 us; speedup vs baseline: 1.6111x; 1.0050x over previous
//
#include <hip/hip_runtime.h>

// ---------------------------------------------------------------------------
// MaskAttentionHead v21: qkv = in-wave counted-vmcnt pipeline (T3+T4 port).
//  Evidence: v15's __syncthreads emits s_waitcnt vmcnt(0) -> drains the
//  just-issued stage(kt+1) HBM loads EVERY K-step (m97's documented barrier
//  drain). v20 (producer wave) was neutral because consumers idled at tile
//  granularity anyway. v21 keeps v15's 4-wave symmetric structure but:
//   - raw s_barrier, manual counted s_waitcnt vmcnt(20/16/0): stage(kt+1),
//     stage(kt+2) stay in flight ACROSS barriers (depth-2 prefetch)
//   - per-iter issue order pinned (sched_barrier(0)): bw(kt+1) -> stage(kt+2)
//     -> vmcnt -> barrier -> compute(kt); counts derived from per-wave queue
//     (stage=4 ops, bw=12 ops)
//   - 4 LDS slots (64KB): stage(kt+2) never aliases a slot a slow wave still
//     reads (mod-4 separation), 2 blocks/CU retained
//   - bw fragments double-buffered in regs (VGPR ~166, >=2 waves/SIMD ok)
//  flash, pack_w: exact v15 bodies.
// ws: WF 384KB | Qg 2MB | KF 2MB | VF 2MB  (~6.7MB)
// ---------------------------------------------------------------------------

typedef __attribute__((ext_vector_type(8))) short v8s;           // 8 x bf16 (MFMA operand)
typedef __attribute__((ext_vector_type(4))) float v4f;           // MFMA 16x16 C/D
typedef __attribute__((ext_vector_type(4))) float f4;            // 4 x f32
typedef __attribute__((ext_vector_type(8))) float f8;            // 8 x f32
typedef __attribute__((ext_vector_type(4))) __bf16 bf4;          // 4 x bf16
typedef __attribute__((ext_vector_type(8))) __bf16 bf8;          // 8 x bf16
typedef __attribute__((ext_vector_type(4))) unsigned short u4;   // 4 x u16

// f32x4 -> bf16x4 (RNE, HW packed cvt on gfx950), as raw u16 lanes.
static __device__ __forceinline__ u4 cvt4(f4 v) {
  return __builtin_bit_cast(u4, __builtin_convertvector(v, bf4));
}

// f32x8 -> bf16x8 as an MFMA A/B operand.
static __device__ __forceinline__ v8s cvt8(f4 lo, f4 hi) {
  f8 ff = __builtin_shufflevector(lo, hi, 0, 1, 2, 3, 4, 5, 6, 7);
  return __builtin_bit_cast(v8s, __builtin_convertvector(ff, bf8));
}

// async 16B/lane global->LDS DMA: dst wave-uniform base, lane i -> dst+i*16.
static __device__ __forceinline__ void dma16(const void* src, void* dst) {
  __builtin_amdgcn_global_load_lds(
      (const __attribute__((address_space(1))) void*)src,
      (__attribute__((address_space(3))) void*)dst, 16, 0, 0);
}

// --- kernel 1: pack weights into WF ----------------------------------------
// WF chunk (g*12+nt)*512 (+lane*8) = B-fragment for 32-K group g, n-tile nt:
// lane(quad,colid) holds W[n=nt*16+colid][k=g*32+quad*8+j].  1/8 folded in Wq.
__global__ __launch_bounds__(256) void pack_w(const float* __restrict__ Wq,
                                              const float* __restrict__ Wk,
                                              const float* __restrict__ Wv,
                                              unsigned short* __restrict__ WF) {
  int idx = (blockIdx.x * 256 + threadIdx.x) * 4;  // 192*1024 total
  int row = idx >> 10;
  int k   = idx & 1023;
  const float* src;
  float scale;
  if (row < 64)       { src = Wq + row * 1024 + k;         scale = 0.125f; }
  else if (row < 128) { src = Wk + (row - 64) * 1024 + k;  scale = 1.0f;   }
  else                { src = Wv + (row - 128) * 1024 + k; scale = 1.0f;   }
  f4 f = *(const f4*)src;
  u4 o = cvt4(f * scale);
  size_t off = ((size_t)(k >> 5) * 12 + (row >> 4)) * 512 +
               (((k >> 3) & 3) * 16 + (row & 15)) * 8 + (k & 7);
  *(u4*)(WF + off) = o;
}

// --- kernel 2: QKV projection (counted-vmcnt pipeline) ----------------------
// 512 blocks x 256 threads, 32 rows/block. K in 8 steps of 128. LDS: 4 slots
// of 16KB, slot(kt) = kt&3. LDS unit (r, su) at byte r*512 + su*16 holds
// global unit u = su ^ (r&7) (XOR inside a 128-B line). Wave wv stages its 4
// chunks of tile kt+2 and prefetches bw(kt+1) each iter; s_waitcnt vmcnt(N)
// retires {stage(kt), bw(kt)} while keeping kt+1/kt+2 in flight.
__global__ __launch_bounds__(256) void qkv(const float* __restrict__ x,
                                           const unsigned short* __restrict__ WF,
                                           unsigned short* __restrict__ Qg,
                                           unsigned short* __restrict__ KF,
                                           unsigned short* __restrict__ VF) {
  __shared__ alignas(16) char xs[4][16384];
  const int tid   = threadIdx.x;
  const int lane  = tid & 63;
  const int wv    = tid >> 6;        // 0..3
  const int quad  = lane >> 4;
  const int colid = lane & 15;
  const int row0  = blockIdx.x * 32;

  const char* xB = (const char*)x;
  const unsigned short* wf = WF + lane * 8;

  const int rpar = lane >> 5;          // which of the chunk's two rows
  const int su_l = lane & 31;          // stored unit
  const int c7   = colid & 7;

  v4f acc[6];   // [mg][ntl] = acc[mg*3+ntl]
#pragma unroll
  for (int i = 0; i < 6; i++) acc[i] = (v4f){0.f, 0.f, 0.f, 0.f};

  auto stage = [&](int kt) {           // 4 dma16, slot kt&3
#pragma unroll
    for (int i = 0; i < 4; i++) {
      int j    = wv * 4 + i;           // chunk = rows {2j, 2j+1}
      int rloc = 2 * j + rpar;
      int u    = su_l ^ (rloc & 7);    // in-line XOR swizzle
      const char* src = xB + (size_t)(row0 + rloc) * 4096 + kt * 512 + u * 16;
      dma16(src, &xs[kt & 3][j * 1024]);
    }
  };

  v8s bwA[12], bwB[12];
  auto load_bw = [&](int kt, v8s* dst) {   // 12 global loads (L2-resident WF)
#pragma unroll
    for (int s = 0; s < 4; s++)
#pragma unroll
      for (int ntl = 0; ntl < 3; ntl++)
        dst[s * 3 + ntl] =
            *(const v8s*)(wf + ((size_t)(kt * 4 + s) * 12 + wv * 3 + ntl) * 512);
  };

  // prologue: queue = [stage(0):4, bw(0):12, stage(1):4]
  stage(0);
  load_bw(0, bwA);
  __builtin_amdgcn_sched_barrier(0);
  stage(1);
  __builtin_amdgcn_sched_barrier(0);

#pragma unroll
  for (int kt = 0; kt < 8; kt++) {
    v8s* cur = ((kt & 1) == 0) ? bwA : bwB;
    v8s* nxt = ((kt & 1) == 0) ? bwB : bwA;
    // issue next bw, then next-next stage (order matters for vmcnt counts)
    if (kt < 7) load_bw(kt + 1, nxt);
    __builtin_amdgcn_sched_barrier(0);
    if (kt < 6) stage(kt + 2);
    __builtin_amdgcn_sched_barrier(0);
    // retire {stage(kt), bw(kt)}; keep kt+1 / kt+2 in flight.
    // youngers of bw(kt): kt<=5 -> stage(kt+1)4 + bw(kt+1)12 + stage(kt+2)4 = 20
    //                     kt==6 -> stage(7)4 + bw(7)12 = 16 ; kt==7 -> 0
    if (kt < 6)      asm volatile("s_waitcnt vmcnt(20)" ::: "memory");
    else if (kt == 6) asm volatile("s_waitcnt vmcnt(16)" ::: "memory");
    else              asm volatile("s_waitcnt vmcnt(0)"  ::: "memory");
    __builtin_amdgcn_sched_barrier(0);
    __builtin_amdgcn_s_barrier();        // all waves' stage(kt) landed
    __builtin_amdgcn_sched_barrier(0);
    const int slot = kt & 3;
#pragma unroll
    for (int s = 0; s < 4; s++) {
#pragma unroll
      for (int mg = 0; mg < 2; mg++) {
        const int rr = mg * 16 + colid;
        const int u0 = s * 8 + quad * 2;
        f4 f0 = *(const f4*)(&xs[slot][rr * 512 + (u0 ^ c7) * 16]);
        f4 f1 = *(const f4*)(&xs[slot][rr * 512 + ((u0 + 1) ^ c7) * 16]);
        v8s a = cvt8(f0, f1);
#pragma unroll
        for (int ntl = 0; ntl < 3; ntl++)
          acc[mg * 3 + ntl] =
              __builtin_amdgcn_mfma_f32_16x16x32_bf16(a, cur[s * 3 + ntl],
                                                      acc[mg * 3 + ntl], 0, 0, 0);
      }
    }
    __builtin_amdgcn_sched_barrier(0);   // keep compute(kt) inside its epoch
  }

  // epilogue: wave wv stores n-tiles wv*3..wv*3+2 for both m-groups
#pragma unroll
  for (int ntl = 0; ntl < 3; ntl++) {
    const int nt = wv * 3 + ntl;
#pragma unroll
    for (int mg = 0; mg < 2; mg++) {
      const int trow_base = row0 + mg * 16 + quad * 4;
      const v4f av = acc[mg * 3 + ntl];
      u4 cc = cvt4((f4){av[0], av[1], av[2], av[3]});
      if (nt < 4) {
#pragma unroll
        for (int r = 0; r < 4; r++)
          Qg[(size_t)(trow_base + r) * 64 + nt * 16 + colid] = cc[r];
      } else if (nt < 8) {
        int half = (nt - 4) >> 1;
        int q_f  = ((nt - 4) * 2 + (colid >> 3)) & 3;
        int j    = colid & 7;
#pragma unroll
        for (int r = 0; r < 4; r++) {
          int t  = trow_base + r;
          int b  = t >> 12, tl = t & 4095;
          int si = tl >> 6, sl = tl & 63;
          KF[((size_t)(b * 64 + si) * 8 + (sl >> 4) * 2 + half) * 512 +
             (q_f * 16 + (sl & 15)) * 8 + j] = cc[r];
        }
      } else {
#pragma unroll
        for (int r = 0; r < 4; r++) {
          int t  = trow_base + r;
          int b  = t >> 12, tl = t & 4095;
          int si = tl >> 6;
          int half = (tl >> 5) & 1, q_f = (tl >> 3) & 3, j = tl & 7;
          VF[((size_t)(b * 64 + si) * 8 + (nt - 8) * 2 + half) * 512 +
             (q_f * 16 + colid) * 8 + j] = cc[r];
        }
      }
    }
  }
}

// --- kernel 3: causal flash, BM=32/wave, 4-way si-split (v15 body) ----------
__global__ __launch_bounds__(256, 2) void flash(const unsigned short* __restrict__ Qg,
                                                const unsigned short* __restrict__ KF,
                                                const unsigned short* __restrict__ VF,
                                                float* __restrict__ out) {
  __shared__ alignas(16) char smem[4 * 32 * 68 * 4 + 4 * 32 * 4];
  unsigned short* pl = (unsigned short*)smem;
  float* redf = (float*)smem;
  float* lred = (float*)(smem + 4 * 32 * 68 * 4);

  const int tid   = threadIdx.x;
  const int lane  = tid & 63;
  const int wv    = tid >> 6;               // si-split id 0..3
  const int quad  = lane >> 4;
  const int colid = lane & 15;
  const int qt32  = 127 - (int)(blockIdx.x >> 2);   // longest-first
  const int b     = blockIdx.x & 3;
  const int bT    = b * 4096;
  const int row00 = qt32 * 32;
  const int qimax = (row00 + 31) >> 6;

  v8s qf[2][2];
#pragma unroll
  for (int mt = 0; mt < 2; mt++) {
    const unsigned short* qrow =
        Qg + (size_t)(bT + row00 + mt * 16 + colid) * 64 + quad * 8;
    qf[mt][0] = *(const v8s*)(qrow);
    qf[mt][1] = *(const v8s*)(qrow + 32);
  }

  v8s ones;
#pragma unroll
  for (int j = 0; j < 8; j++) ones[j] = (short)0x3F80;  // bf16 1.0

  v4f o[2][4];
#pragma unroll
  for (int mt = 0; mt < 2; mt++)
#pragma unroll
    for (int i = 0; i < 4; i++) o[mt][i] = (v4f){0.f, 0.f, 0.f, 0.f};
  v4f lac[2];
  lac[0] = (v4f){0.f, 0.f, 0.f, 0.f};
  lac[1] = (v4f){0.f, 0.f, 0.f, 0.f};

  const unsigned short* kb0 = KF + (size_t)b * 64 * 4096 + lane * 8;
  const unsigned short* vb0 = VF + (size_t)b * 64 * 4096 + lane * 8;

  for (int si = wv; si <= qimax; si += 4) {
    const unsigned short* ktile = kb0 + (size_t)si * 4096;
    const unsigned short* vtile = vb0 + (size_t)si * 4096;
    v8s ck[8], cv[8];
#pragma unroll
    for (int c = 0; c < 8; c++) ck[c] = *(const v8s*)(ktile + (size_t)c * 512);
#pragma unroll
    for (int c = 0; c < 8; c++) cv[c] = *(const v8s*)(vtile + (size_t)c * 512);

#pragma unroll
    for (int mt = 0; mt < 2; mt++) {
      v4f s[4];
#pragma unroll
      for (int i = 0; i < 4; i++) s[i] = (v4f){0.f, 0.f, 0.f, 0.f};
#pragma unroll
      for (int nt = 0; nt < 4; nt++) {
        s[nt] = __builtin_amdgcn_mfma_f32_16x16x32_bf16(qf[mt][0], ck[2 * nt], s[nt], 0, 0, 0);
        s[nt] = __builtin_amdgcn_mfma_f32_16x16x32_bf16(qf[mt][1], ck[2 * nt + 1], s[nt], 0, 0, 0);
      }

      if (si == qimax) {    // diagonal-containing tile: causal mask
        int rowb = row00 + mt * 16 + quad * 4;
        int colb = si * 64;
#pragma unroll
        for (int nt = 0; nt < 4; nt++)
#pragma unroll
          for (int r = 0; r < 4; r++)
            if (colb + nt * 16 + colid > rowb + r) s[nt][r] = -1e30f;
      }

      unsigned short* pw = pl + (wv * 2 + mt) * (16 * 72);
#pragma unroll
      for (int nt = 0; nt < 4; nt++) {
        f4 ev = {__expf(s[nt][0]), __expf(s[nt][1]),
                 __expf(s[nt][2]), __expf(s[nt][3])};
        u4 p = cvt4(ev);
        unsigned short* pb = pw + quad * 4 * 72 + nt * 16 + colid;
        pb[0]   = p[0];
        pb[72]  = p[1];
        pb[144] = p[2];
        pb[216] = p[3];
      }
    }

#pragma unroll
    for (int mt = 0; mt < 2; mt++) {
      unsigned short* pw = pl + (wv * 2 + mt) * (16 * 72);
#pragma unroll
      for (int ks = 0; ks < 64; ks += 32) {
        v8s af = *(const v8s*)(&pw[colid * 72 + ks + quad * 8]);
        lac[mt] = __builtin_amdgcn_mfma_f32_16x16x32_bf16(af, ones, lac[mt], 0, 0, 0);
#pragma unroll
        for (int nt = 0; nt < 4; nt++)
          o[mt][nt] = __builtin_amdgcn_mfma_f32_16x16x32_bf16(
              af, cv[2 * nt + (ks >> 5)], o[mt][nt], 0, 0, 0);
      }
    }
  }

  __syncthreads();
#pragma unroll
  for (int mt = 0; mt < 2; mt++) {
#pragma unroll
    for (int nt = 0; nt < 4; nt++)
#pragma unroll
      for (int r = 0; r < 4; r++)
        redf[(wv * 32 + mt * 16 + quad * 4 + r) * 68 + nt * 16 + colid] = o[mt][nt][r];
    if (colid == 0) {
#pragma unroll
      for (int r = 0; r < 4; r++)
        lred[wv * 32 + mt * 16 + quad * 4 + r] = lac[mt][r];
    }
  }
  __syncthreads();

  {
    int col = tid & 63;
    int r0  = tid >> 6;
#pragma unroll
    for (int rr = 0; rr < 8; rr++) {
      int row = r0 * 8 + rr;
      float sum = 0.f, lsum = 0.f;
#pragma unroll
      for (int w = 0; w < 4; w++) {
        sum  += redf[(w * 32 + row) * 68 + col];
        lsum += lred[w * 32 + row];
      }
      out[(size_t)(bT + row00 + row) * 64 + col] = sum / lsum;
    }
  }
}

extern "C" void kernel_launch(void* const* d_in, const int* in_sizes, int n_in,
                              void* d_out, int out_size, void* d_ws, size_t ws_size,
                              hipStream_t stream) {
  const float* x  = (const float*)d_in[0];
  const float* Wq = (const float*)d_in[1];
  const float* Wk = (const float*)d_in[2];
  const float* Wv = (const float*)d_in[3];
  float* out = (float*)d_out;

  unsigned short* WF = (unsigned short*)d_ws;          // 192*1024
  unsigned short* Qg = WF + 192 * 1024;                // 16384*64 row-major
  unsigned short* KF = Qg + 16384 * 64;                // fragment-linear
  unsigned short* VF = KF + 16384 * 64;                // fragment-linear

  hipLaunchKernelGGL(pack_w, dim3(192), dim3(256), 0, stream, Wq, Wk, Wv, WF);
  hipLaunchKernelGGL(qkv, dim3(512), dim3(256), 0, stream, x, WF, Qg, KF, VF);
  hipLaunchKernelGGL(flash, dim3(512), dim3(256), 0, stream, Qg, KF, VF, out);
}

// Round 9
// 128.130 us; speedup vs baseline: 1.6181x; 1.0043x over previous
//
#include <hip/hip_runtime.h>

// ---------------------------------------------------------------------------
// MaskAttentionHead v22 == v15 (session-best, 126.8us): close-out revert.
//  Session evidence summary:
//   - v18 diagnostics: qkv ~20us (MfmaUtil 12 / VALU 18 / HBM 22 / Occ 21.6
//     -> latency-bound, 70% SIMD idle), flash ~10us, harness-fixed ~95us
//     (41us ws-poison fills + gaps; decomposition retro-fits v13-v21).
//   - Three distinct qkv schedule attacks all NULL within noise:
//     v19 (64-row/512-thr WF amortization, 129.7), v20 (producer/consumer
//     wave, 129.3), v21 (counted-vmcnt depth-2 pipeline, 128.7).
//   - v18's qkv x4 scaled linearly despite L3-resident reps -> issue/latency
//     bound, not BW bound; prefetch depth cannot pay.
//  Conclusion: remaining addressable headroom (<~14us of 126.8) is gated
//  behind a latency mechanism insensitive to intra-kernel scheduling; the
//  rest is harness-fixed. This file restores the measured-best source.
// ws: WF 384KB | Qg 2MB | KF 2MB | VF 2MB  (~6.7MB)
// ---------------------------------------------------------------------------

typedef __attribute__((ext_vector_type(8))) short v8s;           // 8 x bf16 (MFMA operand)
typedef __attribute__((ext_vector_type(4))) float v4f;           // MFMA 16x16 C/D
typedef __attribute__((ext_vector_type(4))) float f4;            // 4 x f32
typedef __attribute__((ext_vector_type(8))) float f8;            // 8 x f32
typedef __attribute__((ext_vector_type(4))) __bf16 bf4;          // 4 x bf16
typedef __attribute__((ext_vector_type(8))) __bf16 bf8;          // 8 x bf16
typedef __attribute__((ext_vector_type(4))) unsigned short u4;   // 4 x u16

// f32x4 -> bf16x4 (RNE, HW packed cvt on gfx950), as raw u16 lanes.
static __device__ __forceinline__ u4 cvt4(f4 v) {
  return __builtin_bit_cast(u4, __builtin_convertvector(v, bf4));
}

// f32x8 -> bf16x8 as an MFMA A/B operand.
static __device__ __forceinline__ v8s cvt8(f4 lo, f4 hi) {
  f8 ff = __builtin_shufflevector(lo, hi, 0, 1, 2, 3, 4, 5, 6, 7);
  return __builtin_bit_cast(v8s, __builtin_convertvector(ff, bf8));
}

// async 16B/lane global->LDS DMA: dst wave-uniform base, lane i -> dst+i*16.
static __device__ __forceinline__ void dma16(const void* src, void* dst) {
  __builtin_amdgcn_global_load_lds(
      (const __attribute__((address_space(1))) void*)src,
      (__attribute__((address_space(3))) void*)dst, 16, 0, 0);
}

// --- kernel 1: pack weights into WF ----------------------------------------
// WF chunk (g*12+nt)*512 (+lane*8) = B-fragment for 32-K group g, n-tile nt:
// lane(quad,colid) holds W[n=nt*16+colid][k=g*32+quad*8+j].  1/8 folded in Wq.
__global__ __launch_bounds__(256) void pack_w(const float* __restrict__ Wq,
                                              const float* __restrict__ Wk,
                                              const float* __restrict__ Wv,
                                              unsigned short* __restrict__ WF) {
  int idx = (blockIdx.x * 256 + threadIdx.x) * 4;  // 192*1024 total
  int row = idx >> 10;
  int k   = idx & 1023;
  const float* src;
  float scale;
  if (row < 64)       { src = Wq + row * 1024 + k;         scale = 0.125f; }
  else if (row < 128) { src = Wk + (row - 64) * 1024 + k;  scale = 1.0f;   }
  else                { src = Wv + (row - 128) * 1024 + k; scale = 1.0f;   }
  f4 f = *(const f4*)src;
  u4 o = cvt4(f * scale);
  size_t off = ((size_t)(k >> 5) * 12 + (row >> 4)) * 512 +
               (((k >> 3) & 3) * 16 + (row & 15)) * 8 + (k & 7);
  *(u4*)(WF + off) = o;
}

// --- kernel 2: QKV projection ----------------------------------------------
// 512 blocks x 256 threads, 32 rows/block. K in 8 steps of 128 (= 32 16-B
// units/row/step). LDS unit (r, su) at byte r*512 + su*16 holds global unit
// u = su ^ (r&7)  (XOR stays inside a 128-B line -> DMA coalescing intact,
// ds_read banks spread). Wave wv stages chunks j in [wv*4,wv*4+4) (chunk j =
// rows {2j,2j+1}); computes n-tiles {wv*3..wv*3+2} for both m-groups.
__global__ __launch_bounds__(256) void qkv(const float* __restrict__ x,
                                           const unsigned short* __restrict__ WF,
                                           unsigned short* __restrict__ Qg,
                                           unsigned short* __restrict__ KF,
                                           unsigned short* __restrict__ VF) {
  __shared__ alignas(16) char xs[2][16384];
  const int tid   = threadIdx.x;
  const int lane  = tid & 63;
  const int wv    = tid >> 6;        // 0..3
  const int quad  = lane >> 4;
  const int colid = lane & 15;
  const int row0  = blockIdx.x * 32;

  const char* xB = (const char*)x;
  const unsigned short* wf = WF + lane * 8;

  // per-lane DMA source pieces: rloc = 2j + (lane>>5), su = lane&31
  const int rpar = lane >> 5;          // which of the chunk's two rows
  const int su_l = lane & 31;          // stored unit
  const int c7   = colid & 7;

  v4f acc[6];   // [mg][ntl] = acc[mg*3+ntl]
#pragma unroll
  for (int i = 0; i < 6; i++) acc[i] = (v4f){0.f, 0.f, 0.f, 0.f};

  auto stage = [&](int kt, int slot) {
#pragma unroll
    for (int i = 0; i < 4; i++) {
      int j    = wv * 4 + i;           // chunk = rows {2j, 2j+1}
      int rloc = 2 * j + rpar;
      int u    = su_l ^ (rloc & 7);    // in-line XOR swizzle
      const char* src = xB + (size_t)(row0 + rloc) * 4096 + kt * 512 + u * 16;
      dma16(src, &xs[slot][j * 1024]);
    }
  };

  stage(0, 0);

  for (int kt = 0; kt < 8; kt++) {
    const int slot = kt & 1;
    __syncthreads();                       // drain stage kt
    if (kt < 7) stage(kt + 1, slot ^ 1);   // overlaps compute kt
#pragma unroll
    for (int s = 0; s < 4; s++) {
      const int g = kt * 4 + s;
      v8s bw[3];
#pragma unroll
      for (int ntl = 0; ntl < 3; ntl++)
        bw[ntl] = *(const v8s*)(wf + ((size_t)g * 12 + wv * 3 + ntl) * 512);
#pragma unroll
      for (int mg = 0; mg < 2; mg++) {
        const int rr = mg * 16 + colid;
        const int u0 = s * 8 + quad * 2;
        f4 f0 = *(const f4*)(&xs[slot][rr * 512 + (u0 ^ c7) * 16]);
        f4 f1 = *(const f4*)(&xs[slot][rr * 512 + ((u0 + 1) ^ c7) * 16]);
        v8s a = cvt8(f0, f1);
#pragma unroll
        for (int ntl = 0; ntl < 3; ntl++)
          acc[mg * 3 + ntl] =
              __builtin_amdgcn_mfma_f32_16x16x32_bf16(a, bw[ntl], acc[mg * 3 + ntl], 0, 0, 0);
      }
    }
  }

  // epilogue: wave wv stores n-tiles wv*3..wv*3+2 for both m-groups
#pragma unroll
  for (int ntl = 0; ntl < 3; ntl++) {
    const int nt = wv * 3 + ntl;
#pragma unroll
    for (int mg = 0; mg < 2; mg++) {
      const int trow_base = row0 + mg * 16 + quad * 4;
      const v4f av = acc[mg * 3 + ntl];
      u4 cc = cvt4((f4){av[0], av[1], av[2], av[3]});
      if (nt < 4) {
#pragma unroll
        for (int r = 0; r < 4; r++)
          Qg[(size_t)(trow_base + r) * 64 + nt * 16 + colid] = cc[r];
      } else if (nt < 8) {
        int half = (nt - 4) >> 1;
        int q_f  = ((nt - 4) * 2 + (colid >> 3)) & 3;
        int j    = colid & 7;
#pragma unroll
        for (int r = 0; r < 4; r++) {
          int t  = trow_base + r;
          int b  = t >> 12, tl = t & 4095;
          int si = tl >> 6, sl = tl & 63;
          KF[((size_t)(b * 64 + si) * 8 + (sl >> 4) * 2 + half) * 512 +
             (q_f * 16 + (sl & 15)) * 8 + j] = cc[r];
        }
      } else {
#pragma unroll
        for (int r = 0; r < 4; r++) {
          int t  = trow_base + r;
          int b  = t >> 12, tl = t & 4095;
          int si = tl >> 6;
          int half = (tl >> 5) & 1, q_f = (tl >> 3) & 3, j = tl & 7;
          VF[((size_t)(b * 64 + si) * 8 + (nt - 8) * 2 + half) * 512 +
             (q_f * 16 + colid) * 8 + j] = cc[r];
        }
      }
    }
  }
}

// --- kernel 3: causal flash, BM=32/wave, 4-way si-split ---------------------
__global__ __launch_bounds__(256, 2) void flash(const unsigned short* __restrict__ Qg,
                                                const unsigned short* __restrict__ KF,
                                                const unsigned short* __restrict__ VF,
                                                float* __restrict__ out) {
  __shared__ alignas(16) char smem[4 * 32 * 68 * 4 + 4 * 32 * 4];
  unsigned short* pl = (unsigned short*)smem;
  float* redf = (float*)smem;
  float* lred = (float*)(smem + 4 * 32 * 68 * 4);

  const int tid   = threadIdx.x;
  const int lane  = tid & 63;
  const int wv    = tid >> 6;               // si-split id 0..3
  const int quad  = lane >> 4;
  const int colid = lane & 15;
  const int qt32  = 127 - (int)(blockIdx.x >> 2);   // longest-first
  const int b     = blockIdx.x & 3;
  const int bT    = b * 4096;
  const int row00 = qt32 * 32;
  const int qimax = (row00 + 31) >> 6;

  v8s qf[2][2];
#pragma unroll
  for (int mt = 0; mt < 2; mt++) {
    const unsigned short* qrow =
        Qg + (size_t)(bT + row00 + mt * 16 + colid) * 64 + quad * 8;
    qf[mt][0] = *(const v8s*)(qrow);
    qf[mt][1] = *(const v8s*)(qrow + 32);
  }

  v8s ones;
#pragma unroll
  for (int j = 0; j < 8; j++) ones[j] = (short)0x3F80;  // bf16 1.0

  v4f o[2][4];
#pragma unroll
  for (int mt = 0; mt < 2; mt++)
#pragma unroll
    for (int i = 0; i < 4; i++) o[mt][i] = (v4f){0.f, 0.f, 0.f, 0.f};
  v4f lac[2];
  lac[0] = (v4f){0.f, 0.f, 0.f, 0.f};
  lac[1] = (v4f){0.f, 0.f, 0.f, 0.f};

  const unsigned short* kb0 = KF + (size_t)b * 64 * 4096 + lane * 8;
  const unsigned short* vb0 = VF + (size_t)b * 64 * 4096 + lane * 8;

  for (int si = wv; si <= qimax; si += 4) {
    const unsigned short* ktile = kb0 + (size_t)si * 4096;
    const unsigned short* vtile = vb0 + (size_t)si * 4096;
    v8s ck[8], cv[8];
#pragma unroll
    for (int c = 0; c < 8; c++) ck[c] = *(const v8s*)(ktile + (size_t)c * 512);
#pragma unroll
    for (int c = 0; c < 8; c++) cv[c] = *(const v8s*)(vtile + (size_t)c * 512);

#pragma unroll
    for (int mt = 0; mt < 2; mt++) {
      v4f s[4];
#pragma unroll
      for (int i = 0; i < 4; i++) s[i] = (v4f){0.f, 0.f, 0.f, 0.f};
#pragma unroll
      for (int nt = 0; nt < 4; nt++) {
        s[nt] = __builtin_amdgcn_mfma_f32_16x16x32_bf16(qf[mt][0], ck[2 * nt], s[nt], 0, 0, 0);
        s[nt] = __builtin_amdgcn_mfma_f32_16x16x32_bf16(qf[mt][1], ck[2 * nt + 1], s[nt], 0, 0, 0);
      }

      if (si == qimax) {    // diagonal-containing tile: causal mask
        int rowb = row00 + mt * 16 + quad * 4;
        int colb = si * 64;
#pragma unroll
        for (int nt = 0; nt < 4; nt++)
#pragma unroll
          for (int r = 0; r < 4; r++)
            if (colb + nt * 16 + colid > rowb + r) s[nt][r] = -1e30f;
      }

      unsigned short* pw = pl + (wv * 2 + mt) * (16 * 72);
#pragma unroll
      for (int nt = 0; nt < 4; nt++) {
        f4 ev = {__expf(s[nt][0]), __expf(s[nt][1]),
                 __expf(s[nt][2]), __expf(s[nt][3])};
        u4 p = cvt4(ev);
        unsigned short* pb = pw + quad * 4 * 72 + nt * 16 + colid;
        pb[0]   = p[0];
        pb[72]  = p[1];
        pb[144] = p[2];
        pb[216] = p[3];
      }
    }

#pragma unroll
    for (int mt = 0; mt < 2; mt++) {
      unsigned short* pw = pl + (wv * 2 + mt) * (16 * 72);
#pragma unroll
      for (int ks = 0; ks < 64; ks += 32) {
        v8s af = *(const v8s*)(&pw[colid * 72 + ks + quad * 8]);
        lac[mt] = __builtin_amdgcn_mfma_f32_16x16x32_bf16(af, ones, lac[mt], 0, 0, 0);
#pragma unroll
        for (int nt = 0; nt < 4; nt++)
          o[mt][nt] = __builtin_amdgcn_mfma_f32_16x16x32_bf16(
              af, cv[2 * nt + (ks >> 5)], o[mt][nt], 0, 0, 0);
      }
    }
  }

  __syncthreads();
#pragma unroll
  for (int mt = 0; mt < 2; mt++) {
#pragma unroll
    for (int nt = 0; nt < 4; nt++)
#pragma unroll
      for (int r = 0; r < 4; r++)
        redf[(wv * 32 + mt * 16 + quad * 4 + r) * 68 + nt * 16 + colid] = o[mt][nt][r];
    if (colid == 0) {
#pragma unroll
      for (int r = 0; r < 4; r++)
        lred[wv * 32 + mt * 16 + quad * 4 + r] = lac[mt][r];
    }
  }
  __syncthreads();

  {
    int col = tid & 63;
    int r0  = tid >> 6;
#pragma unroll
    for (int rr = 0; rr < 8; rr++) {
      int row = r0 * 8 + rr;
      float sum = 0.f, lsum = 0.f;
#pragma unroll
      for (int w = 0; w < 4; w++) {
        sum  += redf[(w * 32 + row) * 68 + col];
        lsum += lred[w * 32 + row];
      }
      out[(size_t)(bT + row00 + row) * 64 + col] = sum / lsum;
    }
  }
}

extern "C" void kernel_launch(void* const* d_in, const int* in_sizes, int n_in,
                              void* d_out, int out_size, void* d_ws, size_t ws_size,
                              hipStream_t stream) {
  const float* x  = (const float*)d_in[0];
  const float* Wq = (const float*)d_in[1];
  const float* Wk = (const float*)d_in[2];
  const float* Wv = (const float*)d_in[3];
  float* out = (float*)d_out;

  unsigned short* WF = (unsigned short*)d_ws;          // 192*1024
  unsigned short* Qg = WF + 192 * 1024;                // 16384*64 row-major
  unsigned short* KF = Qg + 16384 * 64;                // fragment-linear
  unsigned short* VF = KF + 16384 * 64;                // fragment-linear

  hipLaunchKernelGGL(pack_w, dim3(192), dim3(256), 0, stream, Wq, Wk, Wv, WF);
  hipLaunchKernelGGL(qkv, dim3(512), dim3(256), 0, stream, x, WF, Qg, KF, VF);
  hipLaunchKernelGGL(flash, dim3(512), dim3(256), 0, stream, Qg, KF, VF, out);
}